// Round 5
// baseline (25.979 us; speedup 1.0000x reference)
//
#include <hip/hip_runtime.h>

#define NCOL 2048
#define VEC_PER_ROW (NCOL / 4)      // 512 float4 per row
#define PER_LANE 8                   // 8 float4 per lane per array (8*4*64 = 2048)
#define BLOCK 256                    // 4 waves per block
#define ROWS_PER_WAVE 2

typedef float f32x4 __attribute__((ext_vector_type(4)));

__device__ __forceinline__ float waveReduceMax(float v) {
#pragma unroll
    for (int o = 32; o > 0; o >>= 1) v = fmaxf(v, __shfl_xor(v, o, 64));
    return v;
}
__device__ __forceinline__ float waveReduceSum(float v) {
#pragma unroll
    for (int o = 32; o > 0; o >>= 1) v += __shfl_xor(v, o, 64);
    return v;
}

// Phases 1-3 for one row held entirely in registers (a,b overwritten by exps).
__device__ __forceinline__ void process_row(f32x4 (&a)[PER_LANE], f32x4 (&b)[PER_LANE],
                                            f32x4* __restrict__ lo4, f32x4* __restrict__ up4,
                                            int lane)
{
    // ---- row max over both l and u ----
    float m = -3.402823466e38f;
#pragma unroll
    for (int k = 0; k < PER_LANE; ++k) {
        m = fmaxf(m, fmaxf(fmaxf(a[k].x, a[k].y), fmaxf(a[k].z, a[k].w)));
        m = fmaxf(m, fmaxf(fmaxf(b[k].x, b[k].y), fmaxf(b[k].z, b[k].w)));
    }
    m = waveReduceMax(m);

    // ---- exponentials in place + both row sums ----
    float sl = 0.f, su = 0.f;
#pragma unroll
    for (int k = 0; k < PER_LANE; ++k) {
        a[k].x = __expf(a[k].x - m); a[k].y = __expf(a[k].y - m);
        a[k].z = __expf(a[k].z - m); a[k].w = __expf(a[k].w - m);
        b[k].x = __expf(b[k].x - m); b[k].y = __expf(b[k].y - m);
        b[k].z = __expf(b[k].z - m); b[k].w = __expf(b[k].w - m);
        sl += (a[k].x + a[k].y) + (a[k].z + a[k].w);
        su += (b[k].x + b[k].y) + (b[k].z + b[k].w);
    }
    sl = waveReduceSum(sl);
    su = waveReduceSum(su);

    // ---- ratios + coalesced non-temporal vec4 stores ----
#pragma unroll
    for (int k = 0; k < PER_LANE; ++k) {
        f32x4 o, p;
        o.x = __fdividef(a[k].x, a[k].x + (su - b[k].x));
        o.y = __fdividef(a[k].y, a[k].y + (su - b[k].y));
        o.z = __fdividef(a[k].z, a[k].z + (su - b[k].z));
        o.w = __fdividef(a[k].w, a[k].w + (su - b[k].w));
        p.x = __fdividef(b[k].x, b[k].x + (sl - a[k].x));
        p.y = __fdividef(b[k].y, b[k].y + (sl - a[k].y));
        p.z = __fdividef(b[k].z, b[k].z + (sl - a[k].z));
        p.w = __fdividef(b[k].w, b[k].w + (sl - a[k].w));
        __builtin_nontemporal_store(o, &lo4[lane + 64 * k]);
        __builtin_nontemporal_store(p, &up4[lane + 64 * k]);
    }
}

// One row per 64-lane wave, 2 rows per wave, software-pipelined: all 32 loads
// (both rows) issue up front; row-0 compute waits only on its own 16 loads
// (counted vmcnt), so row-1's HBM latency hides under row-0 compute and the
// wave's read burst is front-loaded / write burst back-loaded.
__global__ __launch_bounds__(BLOCK, 2) void interval_softmax_kernel(
    const float* __restrict__ L, const float* __restrict__ U,
    float* __restrict__ lo, float* __restrict__ up, int half_rows)
{
    const int wave = threadIdx.x >> 6;
    const int lane = threadIdx.x & 63;
    const int w    = blockIdx.x * (BLOCK / 64) + wave;

    const size_t r0 = (size_t)w;
    const size_t r1 = (size_t)w + half_rows;

    const f32x4* L0 = reinterpret_cast<const f32x4*>(L) + r0 * VEC_PER_ROW;
    const f32x4* U0 = reinterpret_cast<const f32x4*>(U) + r0 * VEC_PER_ROW;
    const f32x4* L1 = reinterpret_cast<const f32x4*>(L) + r1 * VEC_PER_ROW;
    const f32x4* U1 = reinterpret_cast<const f32x4*>(U) + r1 * VEC_PER_ROW;

    f32x4 a0[PER_LANE], b0[PER_LANE], a1[PER_LANE], b1[PER_LANE];
#pragma unroll
    for (int k = 0; k < PER_LANE; ++k) a0[k] = L0[lane + 64 * k];
#pragma unroll
    for (int k = 0; k < PER_LANE; ++k) b0[k] = U0[lane + 64 * k];
#pragma unroll
    for (int k = 0; k < PER_LANE; ++k) a1[k] = L1[lane + 64 * k];
#pragma unroll
    for (int k = 0; k < PER_LANE; ++k) b1[k] = U1[lane + 64 * k];

    f32x4* lo0 = reinterpret_cast<f32x4*>(lo) + r0 * VEC_PER_ROW;
    f32x4* up0 = reinterpret_cast<f32x4*>(up) + r0 * VEC_PER_ROW;
    process_row(a0, b0, lo0, up0, lane);

    f32x4* lo1 = reinterpret_cast<f32x4*>(lo) + r1 * VEC_PER_ROW;
    f32x4* up1 = reinterpret_cast<f32x4*>(up) + r1 * VEC_PER_ROW;
    process_row(a1, b1, lo1, up1, lane);
}

extern "C" void kernel_launch(void* const* d_in, const int* in_sizes, int n_in,
                              void* d_out, int out_size, void* d_ws, size_t ws_size,
                              hipStream_t stream) {
    const float* L = (const float*)d_in[0];
    const float* U = (const float*)d_in[1];
    const int rows = in_sizes[0] / NCOL;  // B = 4096
    float* lo = (float*)d_out;
    float* up = lo + (size_t)rows * NCOL;
    const int half_rows = rows / ROWS_PER_WAVE;              // 2048 waves
    const int blocks    = half_rows / (BLOCK / 64);          // 512 blocks
    interval_softmax_kernel<<<blocks, BLOCK, 0, stream>>>(L, U, lo, up, half_rows);
}